// Round 1
// baseline (128.108 us; speedup 1.0000x reference)
//
#include <hip/hip_runtime.h>
#include <stdint.h>
#include <math.h>

#define BLK 1024

constexpr int NPG = 32768;              // nodes per graph
constexpr int L1 = 5, L2 = 64, L3 = 32, L4 = 8;
constexpr int K1 = 328, K2 = 33, K3 = 4;

__device__ __forceinline__ uint32_t mono(float f) {
  uint32_t u = __float_as_uint(f);
  return (u & 0x80000000u) ? ~u : (u | 0x80000000u);
}
__device__ __forceinline__ float imono(uint32_t k) {
  uint32_t u = (k & 0x80000000u) ? (k ^ 0x80000000u) : ~k;
  return __uint_as_float(u);
}

// descending bitonic sort of 512 u64 in LDS; all BLK threads must call
__device__ __forceinline__ void bitonic512_desc(unsigned long long* a, int tid) {
  for (int k = 2; k <= 512; k <<= 1) {
    for (int j = k >> 1; j > 0; j >>= 1) {
      if (tid < 512) {
        int i = tid, ixj = i ^ j;
        if (ixj > i) {
          unsigned long long u = a[i], v = a[ixj];
          bool desc = (i & k) == 0;
          if (desc ? (u < v) : (u > v)) { a[i] = v; a[ixj] = u; }
        }
      }
      __syncthreads();
    }
  }
}

__global__ __launch_bounds__(BLK, 1) void topk_net_kernel(
    const float* __restrict__ x,
    const float* __restrict__ w1,
    const float* __restrict__ W_ih,
    const float* __restrict__ b_ih,
    const float* __restrict__ b_hh,
    const float* __restrict__ w2,
    const float* __restrict__ W2,
    const float* __restrict__ b2,
    const float* __restrict__ w3,
    const float* __restrict__ W3,
    const float* __restrict__ b3,
    float* __restrict__ out) {
  __shared__ __align__(16) uint32_t keybuf[NPG];     // 128 KB, reused as float scratch
  __shared__ unsigned long long comp[512];           // 4 KB
  __shared__ uint32_t hist[256];
  __shared__ float xsel[K1 * L1];                    // selected x rows * score
  __shared__ float sWih[L2 * L1];
  __shared__ float sbih[L2];                         // b_ih + b_hh
  __shared__ float sW2[L3 * 65];                     // stride 65 vs bank conflicts
  __shared__ float sb2[L3];
  __shared__ float sw2[L2];
  __shared__ float sw3[L3];
  __shared__ float sW3[L4 * L3];
  __shared__ float sb3[L4];
  __shared__ unsigned long long s_prefix;
  __shared__ int s_rem;
  __shared__ int s_cnt;
  __shared__ float s_inv[3];

  const int tid = threadIdx.x;
  const int g = blockIdx.x;
  const float* xg = x + (size_t)g * NPG * L1;

  // ---- stage small weights into LDS; compute 1/||w|| norms ----
  for (int i = tid; i < L2 * L1; i += BLK) sWih[i] = W_ih[i];
  for (int i = tid; i < L2; i += BLK) { sbih[i] = b_ih[i] + b_hh[i]; sw2[i] = w2[i]; }
  for (int i = tid; i < L3 * L2; i += BLK) sW2[(i >> 6) * 65 + (i & 63)] = W2[i];
  for (int i = tid; i < L3; i += BLK) { sb2[i] = b2[i]; sw3[i] = w3[i]; }
  for (int i = tid; i < L4 * L3; i += BLK) sW3[i] = W3[i];
  for (int i = tid; i < L4; i += BLK) sb3[i] = b3[i];
  if (tid == 0) {
    float s = 0.f;
    for (int k = 0; k < L1; ++k) s += w1[k] * w1[k];
    s_inv[0] = 1.f / sqrtf(s);
    s_prefix = 0ULL; s_rem = K1; s_cnt = 0;
  } else if (tid == 1) {
    float s = 0.f;
    for (int k = 0; k < L2; ++k) s += w2[k] * w2[k];
    s_inv[1] = 1.f / sqrtf(s);
  } else if (tid == 2) {
    float s = 0.f;
    for (int k = 0; k < L3; ++k) s += w3[k] * w3[k];
    s_inv[2] = 1.f / sqrtf(s);
  }

  const float w10 = w1[0], w11 = w1[1], w12 = w1[2], w13 = w1[3], w14 = w1[4];

  // ---- phase B: score keys for all 32768 nodes (vectorized: 4 nodes / 5 float4 per thread) ----
  for (int grp = tid; grp < NPG / 4; grp += BLK) {
    const float4* p = (const float4*)(xg + (size_t)grp * 20);
    float4 a = p[0], b = p[1], c = p[2], d = p[3], e = p[4];
    float d0 = a.x * w10 + a.y * w11 + a.z * w12 + a.w * w13 + b.x * w14;
    float d1 = b.y * w10 + b.z * w11 + b.w * w12 + c.x * w13 + c.y * w14;
    float d2 = c.z * w10 + c.w * w11 + d.x * w12 + d.y * w13 + d.z * w14;
    float d3 = d.w * w10 + e.x * w11 + e.y * w12 + e.z * w13 + e.w * w14;
    uint4 kq;
    kq.x = mono(d0); kq.y = mono(d1); kq.z = mono(d2); kq.w = mono(d3);
    *(uint4*)&keybuf[grp * 4] = kq;
  }

  // ---- phase C: radix-select exact K1-th largest 48-bit composite ----
  int shift = 40;
  for (int pass = 0; pass < 6; ++pass, shift -= 8) {
    for (int i = tid; i < 256; i += BLK) hist[i] = 0;
    __syncthreads();  // also covers phase-B keybuf visibility on pass 0
    unsigned long long pref = s_prefix;
    for (int i = tid; i < NPG; i += BLK) {
      unsigned long long c =
          ((unsigned long long)keybuf[i] << 16) | (unsigned)(65535 - i);
      if ((c >> (shift + 8)) == pref)
        atomicAdd(&hist[(unsigned)(c >> shift) & 0xFFu], 1u);
    }
    __syncthreads();
    if (tid == 0) {
      int rem = s_rem;
      unsigned cum = 0;
      int bucket = 0;
      for (int b = 255; b >= 0; --b) {
        unsigned h = hist[b];
        if (cum + h >= (unsigned)rem) { bucket = b; break; }
        cum += h;
      }
      s_rem = rem - (int)cum;
      s_prefix = (pref << 8) | (unsigned)bucket;
    }
    __syncthreads();
  }
  const unsigned long long T = s_prefix;  // composites are distinct: exactly K1 have c >= T

  // ---- phase D: collect the K1 winners, sort descending ----
  for (int i = tid; i < NPG; i += BLK) {
    unsigned long long c =
        ((unsigned long long)keybuf[i] << 16) | (unsigned)(65535 - i);
    if (c >= T) {
      int p = atomicAdd(&s_cnt, 1);
      if (p < 512) comp[p] = c;
    }
  }
  __syncthreads();
  int cnt = s_cnt;
  for (int i = tid; i < 512; i += BLK)
    if (i >= cnt) comp[i] = 0ULL;
  __syncthreads();
  bitonic512_desc(comp, tid);

  const float inv1 = s_inv[0], inv2 = s_inv[1], inv3 = s_inv[2];

  // ---- phase E: gather x rows * score; RNNCell -> h[328][64] (reuse keybuf) ----
  for (int p = tid; p < K1 * L1; p += BLK) {
    int j = p / L1, k = p - j * L1;
    unsigned long long c = comp[j];
    int idx = 65535 - (int)(c & 0xFFFFu);
    float sc = tanhf(imono((uint32_t)(c >> 16)) * inv1);
    xsel[p] = xg[(size_t)idx * L1 + k] * sc;
  }
  __syncthreads();
  float* hbuf = (float*)keybuf;  // [K1][65], ends at float index 21320
  for (int p = tid; p < K1 * L2; p += BLK) {
    int row = p >> 6, o = p & 63;
    const float* wr = sWih + o * L1;
    const float* xr = xsel + row * L1;
    float acc = sbih[o];
#pragma unroll
    for (int k = 0; k < L1; ++k) acc += xr[k] * wr[k];
    hbuf[row * 65 + o] = tanhf(acc);
  }
  __syncthreads();

  // ---- phase F: pool2 scores over h, sort, top K2 ----
  for (int j = tid; j < 512; j += BLK) {
    unsigned long long c = 0ULL;
    if (j < K1) {
      const float* hr = hbuf + j * 65;
      float acc = 0.f;
      for (int k = 0; k < L2; ++k) acc += hr[k] * sw2[k];
      c = ((unsigned long long)mono(acc) << 16) | (unsigned)(65535 - j);
    }
    comp[j] = c;
  }
  __syncthreads();
  bitonic512_desc(comp, tid);

  // ---- phase G: x2[33][64] = h[sel] * score2 (placed after hbuf region) ----
  float* x2f = hbuf + K1 * 65;  // 33*65 floats
  for (int p = tid; p < K2 * L2; p += BLK) {
    int j = p >> 6, k = p & 63;
    unsigned long long c = comp[j];
    int row = 65535 - (int)(c & 0xFFFFu);
    float sc = tanhf(imono((uint32_t)(c >> 16)) * inv2);
    x2f[j * 65 + k] = hbuf[row * 65 + k] * sc;
  }
  __syncthreads();

  // ---- phase H: y[33][32] = relu(x2 @ W2^T + b2) ----
  float* yf = x2f + K2 * 65;  // stride 33
  for (int p = tid; p < K2 * L3; p += BLK) {
    int j = p >> 5, o = p & 31;
    const float* xr = x2f + j * 65;
    const float* wr = sW2 + o * 65;
    float acc = sb2[o];
    for (int k = 0; k < L2; ++k) acc += xr[k] * wr[k];
    yf[j * 33 + o] = fmaxf(acc, 0.f);
  }
  __syncthreads();

  // ---- phase I: pool3 scores, sort, top K3 ----
  for (int j = tid; j < 512; j += BLK) {
    unsigned long long c = 0ULL;
    if (j < K2) {
      const float* yr = yf + j * 33;
      float acc = 0.f;
      for (int k = 0; k < L3; ++k) acc += yr[k] * sw3[k];
      c = ((unsigned long long)mono(acc) << 16) | (unsigned)(65535 - j);
    }
    comp[j] = c;
  }
  __syncthreads();
  bitonic512_desc(comp, tid);

  // ---- phase J: out[4][8] = (y[sel]*score3) @ W3^T + b3 ----
  for (int p = tid; p < K3 * L4; p += BLK) {
    int t = p >> 3, o = p & 7;
    unsigned long long c = comp[t];
    int row = 65535 - (int)(c & 0xFFFFu);
    float sc = tanhf(imono((uint32_t)(c >> 16)) * inv3);
    const float* yr = yf + row * 33;
    const float* wr = sW3 + o * L3;
    float acc = sb3[o];
    for (int k = 0; k < L3; ++k) acc += yr[k] * sc * wr[k];
    out[((size_t)g * K3 + t) * L4 + o] = acc;
  }
}

extern "C" void kernel_launch(void* const* d_in, const int* in_sizes, int n_in,
                              void* d_out, int out_size, void* d_ws, size_t ws_size,
                              hipStream_t stream) {
  const float* x    = (const float*)d_in[0];
  // d_in[1] = edge_index (unused), d_in[2] = batch (unused: static contiguous grouping)
  const float* w1   = (const float*)d_in[3];
  const float* W_ih = (const float*)d_in[4];
  const float* b_ih = (const float*)d_in[5];
  const float* b_hh = (const float*)d_in[6];
  const float* w2   = (const float*)d_in[7];
  const float* W2   = (const float*)d_in[8];
  const float* b2   = (const float*)d_in[9];
  const float* w3   = (const float*)d_in[10];
  const float* W3   = (const float*)d_in[11];
  const float* b3   = (const float*)d_in[12];
  float* out = (float*)d_out;

  topk_net_kernel<<<dim3(128), dim3(BLK), 0, stream>>>(
      x, w1, W_ih, b_ih, b_hh, w2, W2, b2, w3, W3, b3, out);
}